// Round 4
// baseline (523.144 us; speedup 1.0000x reference)
//
#include <hip/hip_runtime.h>
#include <cstdint>
#include <cstddef>

// ---------------------------------------------------------------------------
// Types / helpers
// ---------------------------------------------------------------------------
using f32x4  = __attribute__((ext_vector_type(4))) float;
using i32x4v = __attribute__((ext_vector_type(4))) int;
using i32x8v = __attribute__((ext_vector_type(8))) int;

__device__ __forceinline__ unsigned char f2fp8(float f) {
  return (unsigned char)(__builtin_amdgcn_cvt_pk_fp8_f32(f, f, 0, false) & 0xff);
}

// exact dequant of OCP e4m3fn byte (sel selects byte of w)
__device__ __forceinline__ float fp8b0(unsigned int w) {
  return __builtin_amdgcn_cvt_f32_fp8(w, 0);
}
__device__ __forceinline__ float fp8b1(unsigned int w) {
  return __builtin_amdgcn_cvt_f32_fp8(w, 1);
}
__device__ __forceinline__ float fp8b2(unsigned int w) {
  return __builtin_amdgcn_cvt_f32_fp8(w, 2);
}
__device__ __forceinline__ float fp8b3(unsigned int w) {
  return __builtin_amdgcn_cvt_f32_fp8(w, 3);
}

__device__ __forceinline__ float waveRed(float v) {
#pragma unroll
  for (int m = 32; m >= 1; m >>= 1) v += __shfl_xor(v, m, 64);
  return v;
}

// async global->LDS, 16B per lane. LDS dest must be wave-uniform base + lane*16.
__device__ __forceinline__ void gload16(const void* g, void* l) {
  __builtin_amdgcn_global_load_lds(
      (__attribute__((address_space(1))) uint32_t*)(uintptr_t)g,
      (__attribute__((address_space(3))) uint32_t*)(uint32_t*)l,
      16, 0, 0);
}

// ---------------------------------------------------------------------------
// prep_w: fused weight prep + workspace zeroing + b0 copy.
// blocks [0,1024)    : W1 -> fp8
// blocks [1024,1280) : W2 -> fp8
// blocks [1280,1536) : W0 -> fp8 row-major (Bcat8 seg0)
// blocks [1536,1792) : W0^T -> fp8 (LDS-tiled)
// blocks [1792,1792+zb) : zero zr region (zwords)
// blocks [1792+zb, +8)  : biascat[0..2047] = b0
// ---------------------------------------------------------------------------
__global__ __launch_bounds__(256) void prep_w(
    const float4* __restrict__ W1, const float4* __restrict__ W2,
    const float4* __restrict__ W0f4, const float* __restrict__ W0,
    const float* __restrict__ b0,
    uint32_t* __restrict__ W1_8, uint32_t* __restrict__ W2_8,
    uint32_t* __restrict__ W0_8, unsigned char* __restrict__ W0t8,
    float* __restrict__ zr, int zwords, float* __restrict__ biascat) {
  __shared__ unsigned char t8[64][65];
  const int b = blockIdx.x;
  const int tid = threadIdx.x;
  if (b < 1024) {
    for (int i = b * 256 + tid; i < 524288; i += 1024 * 256) {
      float4 v = W1[i];
      int p = __builtin_amdgcn_cvt_pk_fp8_f32(v.x, v.y, 0, false);
      p = __builtin_amdgcn_cvt_pk_fp8_f32(v.z, v.w, p, true);
      W1_8[i] = (uint32_t)p;
    }
  } else if (b < 1280) {
    for (int i = (b - 1024) * 256 + tid; i < 131072; i += 256 * 256) {
      float4 v = W2[i];
      int p = __builtin_amdgcn_cvt_pk_fp8_f32(v.x, v.y, 0, false);
      p = __builtin_amdgcn_cvt_pk_fp8_f32(v.z, v.w, p, true);
      W2_8[i] = (uint32_t)p;
    }
  } else if (b < 1536) {
    for (int i = (b - 1280) * 256 + tid; i < 262144; i += 256 * 256) {
      float4 v = W0f4[i];
      int p = __builtin_amdgcn_cvt_pk_fp8_f32(v.x, v.y, 0, false);
      p = __builtin_amdgcn_cvt_pk_fp8_f32(v.z, v.w, p, true);
      W0_8[i] = (uint32_t)p;
    }
  } else if (b < 1792) {
    // transpose W0 (2048 x 512 fp32) -> W0t8 (512 x 2048 fp8)
    const int t = b - 1536;             // 32 row-tiles x 8 col-tiles
    const int r0 = (t >> 3) * 64, c0 = (t & 7) * 64;
#pragma unroll
    for (int p = 0; p < 16; ++p) {
      const int row = p * 4 + (tid >> 6), col = tid & 63;
      t8[row][col] = f2fp8(W0[(size_t)(r0 + row) * 512 + c0 + col]);
    }
    __syncthreads();
#pragma unroll
    for (int p = 0; p < 16; ++p) {
      const int oc = p * 4 + (tid >> 6), orr = tid & 63;
      W0t8[(size_t)(c0 + oc) * 2048 + r0 + orr] = t8[orr][oc];
    }
  } else {
    const int zb = (zwords + 255) >> 8;
    if (b < 1792 + zb) {
      const int i = (b - 1792) * 256 + tid;
      if (i < zwords) zr[i] = 0.f;
    } else {
      const int i = (b - 1792 - zb) * 256 + tid;
      if (i < 2048) biascat[i] = b0[i];
    }
  }
}

// LDS-histogram label count
__global__ __launch_bounds__(256) void count_k(const int* __restrict__ lab,
                                               int* __restrict__ counts, int n) {
  __shared__ int h[512];
  for (int i = threadIdx.x; i < 512; i += 256) h[i] = 0;
  __syncthreads();
  for (int i = blockIdx.x * 256 + threadIdx.x; i < n; i += gridDim.x * 256)
    atomicAdd(&h[lab[i]], 1);
  __syncthreads();
  for (int i = threadIdx.x; i < 512; i += 256) {
    int v = h[i];
    if (v) atomicAdd(&counts[i], v);
  }
}

// single-wave shuffle scan
__global__ void prefix_k(const int* __restrict__ counts, int* __restrict__ offsets,
                         int* __restrict__ cursor, int nc) {
  const int lane = threadIdx.x;  // 64 threads
  int base = 0;
  for (int c0 = 0; c0 < nc; c0 += 64) {
    int v = counts[c0 + lane];
    int x = v;
#pragma unroll
    for (int d = 1; d < 64; d <<= 1) {
      int y = __shfl_up(x, d, 64);
      if (lane >= d) x += y;
    }
    int excl = base + x - v;
    offsets[c0 + lane] = excl;
    cursor[c0 + lane] = excl;
    base += __shfl(x, 63, 64);
  }
}

__global__ void scatter_k(const int* __restrict__ lab, int* __restrict__ cursor,
                          int* __restrict__ buckets, int n) {
  for (int i = blockIdx.x * 256 + threadIdx.x; i < n; i += gridDim.x * 256) {
    int pos = atomicAdd(&cursor[lab[i]], 1);
    buckets[pos] = i;
  }
}

// per-class sums, 4 blocks per class -> PLAIN stores of partials (no atomics).
// centers4[(c*4+q)*512 + d]; written unconditionally (zeros if range empty),
// so centers4 needs no pre-zeroing. Also scal[0] += batch sum of x^2.
__global__ __launch_bounds__(256) void csum_k(const float* __restrict__ x,
    const int* __restrict__ buckets, const int* __restrict__ offsets,
    const int* __restrict__ counts, float* __restrict__ centers4,
    float* __restrict__ scal) {
  const int c = blockIdx.x >> 2, q = blockIdx.x & 3;
  const int cnt = counts[c];
  const int t = threadIdx.x;
  float sx = 0.f, sy = 0.f, ssq = 0.f;
  if (cnt) {
    const int beg = offsets[c];
    const int lo = beg + (cnt * q) / 4, hi = beg + (cnt * (q + 1)) / 4;
    for (int i = lo; i < hi; ++i) {
      const int row = buckets[i];
      const float2 v = ((const float2*)(x + (size_t)row * 512))[t];
      sx += v.x;
      sy += v.y;
      ssq += v.x * v.x + v.y * v.y;
    }
  }
  float2* dst = (float2*)(centers4 + (size_t)((c << 2) + q) * 512);
  dst[t] = make_float2(sx, sy);
  ssq = waveRed(ssq);
  __shared__ float red[4];
  if ((t & 63) == 0) red[t >> 6] = ssq;
  __syncthreads();
  if (t == 0) {
    const float s = red[0] + red[1] + red[2] + red[3];
    if (s != 0.f) atomicAdd(&scal[0], s);
  }
}

// sum the 4 partials -> centers[c] (for pk_k), plus ||S_c||^2/n_c -> out.
__global__ __launch_bounds__(256) void cnorm_k(const float* __restrict__ centers4,
    float* __restrict__ centers, const int* __restrict__ counts,
    float* __restrict__ out) {
  const int c = blockIdx.x;
  const int t = threadIdx.x;
  const float2* p = (const float2*)(centers4 + (size_t)(c << 2) * 512);
  float2 s = p[t];
  float2 s1 = p[t + 256], s2 = p[t + 512], s3 = p[t + 768];
  s.x += s1.x + s2.x + s3.x;
  s.y += s1.y + s2.y + s3.y;
  ((float2*)(centers + (size_t)c * 512))[t] = s;
  const int cnt = counts[c];
  if (cnt == 0) return;
  float ssq = s.x * s.x + s.y * s.y;
  ssq = waveRed(ssq);
  __shared__ float red[4];
  if ((t & 63) == 0) red[t >> 6] = ssq;
  __syncthreads();
  if (t == 0)
    atomicAdd(out, (red[0] + red[1] + red[2] + red[3]) / (float)cnt);
}

// vout[row] = badd[row] + sum_k W[row,K] vin[k]; one block per row (fp32 exact)
__global__ __launch_bounds__(256) void matvec_k(const float* __restrict__ W,
    const float* __restrict__ vin, const float* __restrict__ badd,
    float* __restrict__ vout, int K) {
  int row = blockIdx.x;
  float s = 0.f;
  for (int k = threadIdx.x; k < K; k += 256) s += W[(size_t)row * K + k] * vin[k];
  s = waveRed(s);
  __shared__ float red[4];
  if ((threadIdx.x & 63) == 0) red[threadIdx.x >> 6] = s;
  __syncthreads();
  if (threadIdx.x == 0) vout[row] = red[0] + red[1] + red[2] + red[3] + badd[row];
}

// ---------------------------------------------------------------------------
// pk class-sum kernel: sum over batch of the label-column logit, per level.
//   sum_r v_label(r) = sum_c [ dot(S_c, dq(fp8 W_cat[col c])) + n_c*b_c ]
// where S_c = exact fp32 class sums (centers). One wave per (level, class).
// ---------------------------------------------------------------------------
__global__ void pk_k(const float* __restrict__ centers,
                     const unsigned char* __restrict__ Bcat8,
                     const float* __restrict__ biascat,
                     const int* __restrict__ counts, float* __restrict__ scal) {
  const int b = blockIdx.x;           // [0, 3*512)
  const int lvl = b >> 9;
  const int c = b & 511;
  const int lane = threadIdx.x;       // 64 threads
  const int cbase = (lvl == 0) ? 0 : (lvl == 1) ? 2048 : 3072;
  const float4* S = (const float4*)(centers + (size_t)c * 512);
  const uint2 wb = ((const uint2*)(Bcat8 + (size_t)(cbase + c) * 512))[lane];
  const float4 s0 = S[lane * 2];
  const float4 s1 = S[lane * 2 + 1];
  float s = s0.x * fp8b0(wb.x) + s0.y * fp8b1(wb.x) +
            s0.z * fp8b2(wb.x) + s0.w * fp8b3(wb.x) +
            s1.x * fp8b0(wb.y) + s1.y * fp8b1(wb.y) +
            s1.z * fp8b2(wb.y) + s1.w * fp8b3(wb.y);
  s = waveRed(s);
  if (lane == 0)
    atomicAdd(&scal[5 + lvl], s + (float)counts[c] * biascat[cbase + c]);
}

// ---------------------------------------------------------------------------
// MX-fp8 GEMM for weight collapse: C[M,N] = A[M,K] @ B[N,K]^T, fp8 out
// (row-major C8, optional transposed Ct8). 128x128 tile, BK=128.
// ---------------------------------------------------------------------------
__global__ __launch_bounds__(256) void gemm8_w(
    const unsigned char* __restrict__ A8, const unsigned char* __restrict__ B8,
    int M, int N, int K, unsigned char* __restrict__ C8,
    unsigned char* __restrict__ Ct8) {
  __shared__ __align__(16) unsigned char As[128 * 128];
  __shared__ __align__(16) unsigned char Bs[128 * 128];
  const int tid = threadIdx.x;
  const int lane = tid & 63;
  const int wave = tid >> 6;
  const int lane16 = lane & 15;
  const int quad = lane >> 4;
  const int wm = (wave >> 1) * 64;
  const int wn = (wave & 1) * 64;
  const int m0 = blockIdx.y * 128;
  const int n0 = blockIdx.x * 128;

  f32x4 acc[4][4] = {};

  int srow[4], goff[4];
#pragma unroll
  for (int q = 0; q < 4; ++q) {
    const int s = tid + q * 256;
    const int row = s >> 3;
    const int c16 = s & 7;
    srow[q] = row;
    goff[q] = (((c16 >> 1) ^ (row & 3)) << 5) + ((c16 & 1) << 4);
  }

  for (int kt = 0; kt < K; kt += 128) {
#pragma unroll
    for (int q = 0; q < 4; ++q) {
      const int s = tid + q * 256;
      gload16(A8 + (size_t)(m0 + srow[q]) * K + kt + goff[q], &As[s * 16]);
      gload16(B8 + (size_t)(n0 + srow[q]) * K + kt + goff[q], &Bs[s * 16]);
    }
    __syncthreads();
    i32x8v a8[4], b8[4];
#pragma unroll
    for (int i = 0; i < 4; ++i) {
      const int row = i * 16 + lane16;
      const int sc = quad ^ (row & 3);
      const unsigned char* pa = &As[row * 128 + sc * 32];
      const i32x4v lo = *(const i32x4v*)pa;
      const i32x4v hi = *(const i32x4v*)(pa + 16);
      a8[i] = (i32x8v){lo[0], lo[1], lo[2], lo[3], hi[0], hi[1], hi[2], hi[3]};
    }
#pragma unroll
    for (int j = 0; j < 4; ++j) {
      const int row = j * 16 + lane16;
      const int sc = quad ^ (row & 3);
      const unsigned char* pb = &Bs[row * 128 + sc * 32];
      const i32x4v lo = *(const i32x4v*)pb;
      const i32x4v hi = *(const i32x4v*)(pb + 16);
      b8[j] = (i32x8v){lo[0], lo[1], lo[2], lo[3], hi[0], hi[1], hi[2], hi[3]};
    }
#pragma unroll
    for (int i = 0; i < 4; ++i)
#pragma unroll
      for (int j = 0; j < 4; ++j)
        acc[i][j] = __builtin_amdgcn_mfma_scale_f32_16x16x128_f8f6f4(
            a8[i], b8[j], acc[i][j], 0, 0, 0, 0x7f7f7f7f, 0, 0x7f7f7f7f);
    __syncthreads();
  }
#pragma unroll
  for (int i = 0; i < 4; ++i)
#pragma unroll
    for (int r = 0; r < 4; ++r) {
      const int rowg = m0 + wm + i * 16 + quad * 4 + r;
#pragma unroll
      for (int j = 0; j < 4; ++j) {
        const int colg = n0 + wn + j * 16 + lane16;
        const unsigned char v8 = f2fp8(acc[i][j][r]);
        C8[(size_t)rowg * N + colg] = v8;
        if (Ct8) Ct8[(size_t)colg * M + rowg] = v8;
      }
    }
}

// ---------------------------------------------------------------------------
// reorder: Bcat8 row-major (3584 x 512) -> fragment-major Bp, LDS-friendly.
// Chunk g = tile64*4 + kt is 8KB contiguous. Within a chunk, fragment j
// occupies [j*2048, j*2048+2048). Within a fragment, lane l's 32B k-window
// is SPLIT: k-bytes 0-15 at l*16, k-bytes 16-31 at 1024 + l*16, so the
// gemm's two ds_read_b128 per fragment are lane-consecutive (conflict-free).
// lane l = ((k>>5)&3)*16 + (col&15).
// ---------------------------------------------------------------------------
__global__ void reorder_k(const unsigned char* __restrict__ in,
                          unsigned char* __restrict__ out) {
  const int id = blockIdx.x * 256 + threadIdx.x;   // 57344 chunks
  const int col = id >> 4;
  const int k32 = id & 15;                         // k/32
  const int kt = k32 >> 2, quad = k32 & 3;
  const int l = quad * 16 + (col & 15);
  const size_t src = (size_t)col * 512 + k32 * 32;
  const size_t fragbase = (size_t)(col >> 6) * 32768 + (size_t)kt * 8192 +
                          (size_t)((col >> 4) & 3) * 2048;
  const uint4 a = *(const uint4*)(in + src);        // k-bytes 0-15
  const uint4 b = *(const uint4*)(in + src + 16);   // k-bytes 16-31
  *(uint4*)(out + fragbase + l * 16) = a;
  *(uint4*)(out + fragbase + 1024 + l * 16) = b;
}

// ---------------------------------------------------------------------------
// Streaming fused logits+CE GEMM — software-pipelined (T3/T4/T5) variant.
// Block = 256 threads = 4 waves; wave owns 32 rows of x (A in VGPRs).
// Grid = B/128 = 512 blocks -> 2 blocks/CU.
//
// Schedule per k-step g (all waits target ops issued >= 1 full step earlier):
//   1. issue gload_lds for chunk g+3 into ring slot (g+3)&3   [2 loads]
//   2. s_waitcnt vmcnt(4)   -> chunk g+1 (staged at step g-2) resident
//   3. raw s_barrier        -> all 4 waves' slices of g+1 resident
//   4. ds_read chunk g+1 -> bNXT (8 x b128, NO wait)
//   5. s_waitcnt lgkmcnt(8) + sched_barrier(0)  -> bCUR (read at g-1) ready
//   6. setprio(1); 8 x MFMA on bCUR; setprio(0)
// bX/bY are explicitly named ping-pong buffers (rule #20); ring slots are
// compile-time ((ks+3)&3 / (ks+1)&3, since 4 steps/tile). The k-stream
// wraps at the end (<=3 junk stages/reads, never consumed, always in-bounds).
// ---------------------------------------------------------------------------
__global__ __launch_bounds__(256, 2) void gemm_ce8(
    const float* __restrict__ x, const unsigned char* __restrict__ Bp,
    const float* __restrict__ bias, float* __restrict__ scal) {
  __shared__ __align__(16) unsigned char Bl[4][8192];
  __shared__ float biasl[3584];
  const int tid = threadIdx.x;
  const int lane = tid & 63;
  const int wave = tid >> 6;
  const int lane16 = lane & 15;
  const int quad = lane >> 4;
  const int m0 = blockIdx.x * 128 + wave * 32;

  // ---- bias -> LDS (once) ----
  for (int i = tid; i < 3584; i += 256) biasl[i] = bias[i];

  // ---- A: 32 rows x 512 fp8 in VGPRs, fused fp32->fp8 ----
  i32x8v a[2][4];
#pragma unroll
  for (int i = 0; i < 2; ++i) {
    const float* xr = x + (size_t)(m0 + i * 16 + lane16) * 512 + quad * 32;
#pragma unroll
    for (int kt = 0; kt < 4; ++kt) {
      const float4* p4 = (const float4*)(xr + kt * 128);
      int d[8];
#pragma unroll
      for (int p = 0; p < 8; ++p) {
        const float4 f = p4[p];
        int w_ = __builtin_amdgcn_cvt_pk_fp8_f32(f.x, f.y, 0, false);
        w_ = __builtin_amdgcn_cvt_pk_fp8_f32(f.z, f.w, w_, true);
        d[p] = w_;
      }
      a[i][kt] = (i32x8v){d[0], d[1], d[2], d[3], d[4], d[5], d[6], d[7]};
    }
  }
  __syncthreads();  // biasl visible; vmcnt/lgkmcnt drained (full sync)

  // ---- pipeline prologue: stage chunks 0,1,2 ----
  const int soff = wave * 2048 + lane * 16;
  const unsigned char* bsrc = Bp + soff;
#pragma unroll
  for (int c = 0; c < 3; ++c) {
    gload16(bsrc, &Bl[c][soff]);
    gload16(bsrc + 1024, &Bl[c][soff + 1024]);
    bsrc += 8192;
  }
  int sc = 3;  // chunk index bsrc points at (224 chunks total)
  asm volatile("s_waitcnt vmcnt(4)" ::: "memory");  // chunk 0 resident
  __builtin_amdgcn_s_barrier();

  // preload chunk 0 -> bX (waited by first KSTEP's lgkmcnt(8))
  i32x8v bX[4], bY[4];
  {
    const unsigned char* bb = &Bl[0][0];
#pragma unroll
    for (int j = 0; j < 4; ++j) {
      const i32x4v lo = *(const i32x4v*)(bb + j * 2048 + lane * 16);
      const i32x4v hi = *(const i32x4v*)(bb + j * 2048 + 1024 + lane * 16);
      bX[j] = (i32x8v){lo[0], lo[1], lo[2], lo[3], hi[0], hi[1], hi[2], hi[3]};
    }
  }

  float es[8];
#pragma unroll
  for (int k = 0; k < 8; ++k) es[k] = 0.f;

#define KSTEP(KS, BCUR, BNXT)                                                 \
  {                                                                           \
    gload16(bsrc, &Bl[(KS + 3) & 3][soff]);                                   \
    gload16(bsrc + 1024, &Bl[(KS + 3) & 3][soff + 1024]);                     \
    bsrc += 8192;                                                             \
    if (++sc == 224) { sc = 0; bsrc = Bp + soff; }                            \
    asm volatile("s_waitcnt vmcnt(4)" ::: "memory");                          \
    __builtin_amdgcn_s_barrier();                                             \
    {                                                                         \
      const unsigned char* bb = &Bl[(KS + 1) & 3][0];                         \
      _Pragma("unroll")                                                       \
      for (int j = 0; j < 4; ++j) {                                           \
        const i32x4v lo = *(const i32x4v*)(bb + j * 2048 + lane * 16);        \
        const i32x4v hi = *(const i32x4v*)(bb + j * 2048 + 1024 + lane * 16); \
        BNXT[j] = (i32x8v){lo[0], lo[1], lo[2], lo[3],                        \
                           hi[0], hi[1], hi[2], hi[3]};                       \
      }                                                                       \
    }                                                                         \
    asm volatile("s_waitcnt lgkmcnt(8)" ::: "memory");                        \
    __builtin_amdgcn_sched_barrier(0);                                        \
    __builtin_amdgcn_s_setprio(1);                                            \
    _Pragma("unroll")                                                         \
    for (int i = 0; i < 2; ++i)                                               \
      _Pragma("unroll")                                                       \
      for (int j = 0; j < 4; ++j)                                             \
        acc[i][j] = __builtin_amdgcn_mfma_scale_f32_16x16x128_f8f6f4(         \
            a[i][KS], BCUR[j], acc[i][j], 0, 0, 0, 0x7f7f7f7f, 0,             \
            0x7f7f7f7f);                                                      \
    __builtin_amdgcn_s_setprio(0);                                            \
  }

  int tile = 0;
#pragma unroll 1
  for (int lvl = 0; lvl < 3; ++lvl) {
    const int nt = (lvl == 0) ? 32 : (lvl == 1) ? 16 : 8;
#pragma unroll 1
    for (int t = 0; t < nt; ++t, ++tile) {
      f32x4 acc[2][4] = {};
      KSTEP(0, bX, bY)
      KSTEP(1, bY, bX)
      KSTEP(2, bX, bY)
      KSTEP(3, bY, bX)
      // ---- register CE epilogue (bias from LDS; pk handled by pk_k) ----
      float bj[4];
#pragma unroll
      for (int j = 0; j < 4; ++j) bj[j] = biasl[tile * 64 + j * 16 + lane16];
#pragma unroll
      for (int i = 0; i < 2; ++i)
#pragma unroll
        for (int r = 0; r < 4; ++r) {
          float e = 0.f;
#pragma unroll
          for (int j = 0; j < 4; ++j) e += __expf(acc[i][j][r] + bj[j]);
          es[i * 4 + r] += e;
        }
    }
    // ---- level close: reduce es over lane16, log, accumulate ----
    float ls = 0.f;
#pragma unroll
    for (int k = 0; k < 8; ++k) {
      float tot = es[k];
      tot += __shfl_xor(tot, 1, 64);
      tot += __shfl_xor(tot, 2, 64);
      tot += __shfl_xor(tot, 4, 64);
      tot += __shfl_xor(tot, 8, 64);
      if (lane16 == 0) ls += __logf(tot);
      es[k] = 0.f;
    }
    ls = waveRed(ls);
    if (lane == 0) atomicAdd(&scal[2 + lvl], ls);
  }
#undef KSTEP
}

// scal: [0]=sumsq_x [1]=sum ||sums_c||^2/n_c [2..4]=logsumexp sums [5..7]=pk sums
__global__ void fin_k(const float* __restrict__ scal, const float* __restrict__ lam,
                      float* __restrict__ out, float invB) {
  if (threadIdx.x == 0 && blockIdx.x == 0)
    out[0] = lam[0] * (scal[0] - scal[1]) +
             (lam[1] * (scal[2] - scal[5]) + lam[2] * (scal[3] - scal[6]) +
              lam[3] * (scal[4] - scal[7])) * invB;
}

// ---------------------------------------------------------------------------
// Launch
// ---------------------------------------------------------------------------
extern "C" void kernel_launch(void* const* d_in, const int* in_sizes, int n_in,
                              void* d_out, int out_size, void* d_ws, size_t ws_size,
                              hipStream_t stream) {
  const float* x   = (const float*)d_in[0];
  const float* W0  = (const float*)d_in[1];
  const float* b0  = (const float*)d_in[2];
  const float* W1  = (const float*)d_in[3];
  const float* b1  = (const float*)d_in[4];
  const float* W2  = (const float*)d_in[5];
  const float* b2  = (const float*)d_in[6];
  const float* lam = (const float*)d_in[7];
  const int*   lab = (const int*)d_in[8];

  const int Bsz = in_sizes[8];         // 65536
  const int D   = in_sizes[0] / Bsz;   // 512
  const int N0  = in_sizes[2];         // 2048
  const int N1  = in_sizes[4];         // 1024
  const int N2  = in_sizes[6];         // 512
  const int Ncat = N0 + N1 + N2;       // 3584
  const int NCLS = 512;

  char* w = (char*)d_ws;
  size_t off = 0;
  auto alloc = [&](size_t bytes) -> void* {
    void* p = w + off;
    off += (bytes + 255) & ~(size_t)255;
    return p;
  };

  unsigned char* Bcat8 = (unsigned char*)alloc((size_t)Ncat * D);         // row-major
  unsigned char* Bp    = (unsigned char*)alloc((size_t)Ncat * D + 16384); // frag-major (+slack)
  unsigned char* W1_8  = (unsigned char*)alloc((size_t)N1 * N0);
  unsigned char* W2_8  = (unsigned char*)alloc((size_t)N2 * N1);
  unsigned char* W0t8  = (unsigned char*)alloc((size_t)D * N0);
  unsigned char* M1t8  = (unsigned char*)alloc((size_t)D * N1);
  float* biascat  = (float*)alloc((size_t)Ncat * 4);
  int* offsets = (int*)alloc(NCLS * 4);
  int* cursor  = (int*)alloc(NCLS * 4);
  int* buckets = (int*)alloc((size_t)Bsz * 4);
  float* centers4 = (float*)alloc((size_t)NCLS * 512 * 4 * 4);  // partials (no zero)
  float* centers  = (float*)alloc((size_t)NCLS * 512 * 4);      // summed (no zero)
  // zero region: counts(512i) | scal(8f)
  const int zwords = NCLS + 8;
  char* zr = (char*)alloc((size_t)zwords * 4);
  int*   counts  = (int*)zr;
  float* scal    = (float*)(zr + NCLS * 4);
  (void)ws_size; (void)n_in; (void)out_size;

  // fused prep: weight fp8 conversions + W0^T + zero + b0 copy
  const int zb = (zwords + 255) / 256;
  prep_w<<<dim3(1792 + zb + 8), dim3(256), 0, stream>>>(
      (const float4*)W1, (const float4*)W2, (const float4*)W0, W0, b0,
      (uint32_t*)W1_8, (uint32_t*)W2_8, (uint32_t*)Bcat8, W0t8,
      (float*)zr, zwords, biascat);

  // center-loss bucketing + class partial sums (plain stores) + batch sumsq
  count_k<<<dim3(32), dim3(256), 0, stream>>>(lab, counts, Bsz);
  prefix_k<<<dim3(1), dim3(64), 0, stream>>>(counts, offsets, cursor, NCLS);
  scatter_k<<<dim3(256), dim3(256), 0, stream>>>(lab, cursor, buckets, Bsz);
  csum_k<<<dim3(4 * NCLS), dim3(256), 0, stream>>>(x, buckets, offsets, counts,
                                                   centers4, scal);
  cnorm_k<<<dim3(NCLS), dim3(256), 0, stream>>>(centers4, centers, counts,
                                                &scal[1]);

  // collapsed biases: biascat = [b0 | b1 + W1 b0 | b2 + W2 c1] (fp32 exact)
  matvec_k<<<dim3(N1), dim3(256), 0, stream>>>(W1, b0, b1, biascat + N0, N0);
  matvec_k<<<dim3(N2), dim3(256), 0, stream>>>(W2, biascat + N0, b2, biascat + N0 + N1, N1);

  // collapsed weights (fp8): M1 = W1@W0 -> Bcat8 seg1 + M1t8; M2 = W2@M1 -> seg2
  gemm8_w<<<dim3(D / 128, N1 / 128), dim3(256), 0, stream>>>(
      W1_8, W0t8, N1, D, N0, Bcat8 + (size_t)N0 * D, M1t8);
  gemm8_w<<<dim3(D / 128, N2 / 128), dim3(256), 0, stream>>>(
      W2_8, M1t8, N2, D, N1, Bcat8 + (size_t)(N0 + N1) * D, nullptr);

  // row-major -> fragment-major (LDS-friendly lo/hi split)
  reorder_k<<<dim3(Ncat * D / 32 / 256), dim3(256), 0, stream>>>(Bcat8, Bp);

  // pk via class-sum identity (needs Bcat8 complete + centers + biascat + counts)
  pk_k<<<dim3(3 * NCLS), dim3(64), 0, stream>>>(centers, Bcat8, biascat,
                                                counts, scal);

  // software-pipelined streaming fused logits+CE (all three levels)
  gemm_ce8<<<dim3(Bsz / 128), dim3(256), 0, stream>>>(x, Bp, biascat, scal);

  fin_k<<<dim3(1), dim3(64), 0, stream>>>(scal, lam, (float*)d_out, 1.f / (float)Bsz);
}

// Round 5
// 519.553 us; speedup vs baseline: 1.0069x; 1.0069x over previous
//
#include <hip/hip_runtime.h>
#include <cstdint>
#include <cstddef>

// ---------------------------------------------------------------------------
// Types / helpers
// ---------------------------------------------------------------------------
using f32x4  = __attribute__((ext_vector_type(4))) float;
using i32x4v = __attribute__((ext_vector_type(4))) int;
using i32x8v = __attribute__((ext_vector_type(8))) int;

__device__ __forceinline__ unsigned char f2fp8(float f) {
  return (unsigned char)(__builtin_amdgcn_cvt_pk_fp8_f32(f, f, 0, false) & 0xff);
}

// exact dequant of OCP e4m3fn byte (sel selects byte of w)
__device__ __forceinline__ float fp8b0(unsigned int w) {
  return __builtin_amdgcn_cvt_f32_fp8(w, 0);
}
__device__ __forceinline__ float fp8b1(unsigned int w) {
  return __builtin_amdgcn_cvt_f32_fp8(w, 1);
}
__device__ __forceinline__ float fp8b2(unsigned int w) {
  return __builtin_amdgcn_cvt_f32_fp8(w, 2);
}
__device__ __forceinline__ float fp8b3(unsigned int w) {
  return __builtin_amdgcn_cvt_f32_fp8(w, 3);
}

__device__ __forceinline__ float waveRed(float v) {
#pragma unroll
  for (int m = 32; m >= 1; m >>= 1) v += __shfl_xor(v, m, 64);
  return v;
}

// async global->LDS, 16B per lane. LDS dest must be wave-uniform base + lane*16.
__device__ __forceinline__ void gload16(const void* g, void* l) {
  __builtin_amdgcn_global_load_lds(
      (__attribute__((address_space(1))) uint32_t*)(uintptr_t)g,
      (__attribute__((address_space(3))) uint32_t*)(uint32_t*)l,
      16, 0, 0);
}

// convert 32 contiguous fp32 -> one i32x8v of fp8 bytes (SSA return value)
__device__ __forceinline__ i32x8v cvt32(const float* p) {
  const float4* p4 = (const float4*)p;
  int d0, d1, d2, d3, d4, d5, d6, d7;
#define CVT1(N)                                                      \
  {                                                                  \
    const float4 f = p4[N];                                          \
    int w_ = __builtin_amdgcn_cvt_pk_fp8_f32(f.x, f.y, 0, false);    \
    w_ = __builtin_amdgcn_cvt_pk_fp8_f32(f.z, f.w, w_, true);        \
    d##N = w_;                                                       \
  }
  CVT1(0) CVT1(1) CVT1(2) CVT1(3) CVT1(4) CVT1(5) CVT1(6) CVT1(7)
#undef CVT1
  return (i32x8v){d0, d1, d2, d3, d4, d5, d6, d7};
}

// read one 32B-per-lane B fragment (lo/hi split layout) from LDS (SSA return)
__device__ __forceinline__ i32x8v ldfrag(const unsigned char* bb, int off) {
  const i32x4v lo = *(const i32x4v*)(bb + off);
  const i32x4v hi = *(const i32x4v*)(bb + off + 1024);
  return (i32x8v){lo[0], lo[1], lo[2], lo[3], hi[0], hi[1], hi[2], hi[3]};
}

// ---------------------------------------------------------------------------
// prep_w: fused weight prep + workspace zeroing + b0 copy.
// ---------------------------------------------------------------------------
__global__ __launch_bounds__(256) void prep_w(
    const float4* __restrict__ W1, const float4* __restrict__ W2,
    const float4* __restrict__ W0f4, const float* __restrict__ W0,
    const float* __restrict__ b0,
    uint32_t* __restrict__ W1_8, uint32_t* __restrict__ W2_8,
    uint32_t* __restrict__ W0_8, unsigned char* __restrict__ W0t8,
    float* __restrict__ zr, int zwords, float* __restrict__ biascat) {
  __shared__ unsigned char t8[64][65];
  const int b = blockIdx.x;
  const int tid = threadIdx.x;
  if (b < 1024) {
    for (int i = b * 256 + tid; i < 524288; i += 1024 * 256) {
      float4 v = W1[i];
      int p = __builtin_amdgcn_cvt_pk_fp8_f32(v.x, v.y, 0, false);
      p = __builtin_amdgcn_cvt_pk_fp8_f32(v.z, v.w, p, true);
      W1_8[i] = (uint32_t)p;
    }
  } else if (b < 1280) {
    for (int i = (b - 1024) * 256 + tid; i < 131072; i += 256 * 256) {
      float4 v = W2[i];
      int p = __builtin_amdgcn_cvt_pk_fp8_f32(v.x, v.y, 0, false);
      p = __builtin_amdgcn_cvt_pk_fp8_f32(v.z, v.w, p, true);
      W2_8[i] = (uint32_t)p;
    }
  } else if (b < 1536) {
    for (int i = (b - 1280) * 256 + tid; i < 262144; i += 256 * 256) {
      float4 v = W0f4[i];
      int p = __builtin_amdgcn_cvt_pk_fp8_f32(v.x, v.y, 0, false);
      p = __builtin_amdgcn_cvt_pk_fp8_f32(v.z, v.w, p, true);
      W0_8[i] = (uint32_t)p;
    }
  } else if (b < 1792) {
    // transpose W0 (2048 x 512 fp32) -> W0t8 (512 x 2048 fp8)
    const int t = b - 1536;             // 32 row-tiles x 8 col-tiles
    const int r0 = (t >> 3) * 64, c0 = (t & 7) * 64;
#pragma unroll
    for (int p = 0; p < 16; ++p) {
      const int row = p * 4 + (tid >> 6), col = tid & 63;
      t8[row][col] = f2fp8(W0[(size_t)(r0 + row) * 512 + c0 + col]);
    }
    __syncthreads();
#pragma unroll
    for (int p = 0; p < 16; ++p) {
      const int oc = p * 4 + (tid >> 6), orr = tid & 63;
      W0t8[(size_t)(c0 + oc) * 2048 + r0 + orr] = t8[orr][oc];
    }
  } else {
    const int zb = (zwords + 255) >> 8;
    if (b < 1792 + zb) {
      const int i = (b - 1792) * 256 + tid;
      if (i < zwords) zr[i] = 0.f;
    } else {
      const int i = (b - 1792 - zb) * 256 + tid;
      if (i < 2048) biascat[i] = b0[i];
    }
  }
}

// LDS-histogram label count
__global__ __launch_bounds__(256) void count_k(const int* __restrict__ lab,
                                               int* __restrict__ counts, int n) {
  __shared__ int h[512];
  for (int i = threadIdx.x; i < 512; i += 256) h[i] = 0;
  __syncthreads();
  for (int i = blockIdx.x * 256 + threadIdx.x; i < n; i += gridDim.x * 256)
    atomicAdd(&h[lab[i]], 1);
  __syncthreads();
  for (int i = threadIdx.x; i < 512; i += 256) {
    int v = h[i];
    if (v) atomicAdd(&counts[i], v);
  }
}

// single-wave shuffle scan
__global__ void prefix_k(const int* __restrict__ counts, int* __restrict__ offsets,
                         int* __restrict__ cursor, int nc) {
  const int lane = threadIdx.x;  // 64 threads
  int base = 0;
  for (int c0 = 0; c0 < nc; c0 += 64) {
    int v = counts[c0 + lane];
    int x = v;
#pragma unroll
    for (int d = 1; d < 64; d <<= 1) {
      int y = __shfl_up(x, d, 64);
      if (lane >= d) x += y;
    }
    int excl = base + x - v;
    offsets[c0 + lane] = excl;
    cursor[c0 + lane] = excl;
    base += __shfl(x, 63, 64);
  }
}

__global__ void scatter_k(const int* __restrict__ lab, int* __restrict__ cursor,
                          int* __restrict__ buckets, int n) {
  for (int i = blockIdx.x * 256 + threadIdx.x; i < n; i += gridDim.x * 256) {
    int pos = atomicAdd(&cursor[lab[i]], 1);
    buckets[pos] = i;
  }
}

// per-class sums, 4 blocks per class -> PLAIN stores of partials (no atomics).
__global__ __launch_bounds__(256) void csum_k(const float* __restrict__ x,
    const int* __restrict__ buckets, const int* __restrict__ offsets,
    const int* __restrict__ counts, float* __restrict__ centers4,
    float* __restrict__ scal) {
  const int c = blockIdx.x >> 2, q = blockIdx.x & 3;
  const int cnt = counts[c];
  const int t = threadIdx.x;
  float sx = 0.f, sy = 0.f, ssq = 0.f;
  if (cnt) {
    const int beg = offsets[c];
    const int lo = beg + (cnt * q) / 4, hi = beg + (cnt * (q + 1)) / 4;
    for (int i = lo; i < hi; ++i) {
      const int row = buckets[i];
      const float2 v = ((const float2*)(x + (size_t)row * 512))[t];
      sx += v.x;
      sy += v.y;
      ssq += v.x * v.x + v.y * v.y;
    }
  }
  float2* dst = (float2*)(centers4 + (size_t)((c << 2) + q) * 512);
  dst[t] = make_float2(sx, sy);
  ssq = waveRed(ssq);
  __shared__ float red[4];
  if ((t & 63) == 0) red[t >> 6] = ssq;
  __syncthreads();
  if (t == 0) {
    const float s = red[0] + red[1] + red[2] + red[3];
    if (s != 0.f) atomicAdd(&scal[0], s);
  }
}

// sum the 4 partials -> centers[c] (for pk_k), plus ||S_c||^2/n_c -> out.
__global__ __launch_bounds__(256) void cnorm_k(const float* __restrict__ centers4,
    float* __restrict__ centers, const int* __restrict__ counts,
    float* __restrict__ out) {
  const int c = blockIdx.x;
  const int t = threadIdx.x;
  const float2* p = (const float2*)(centers4 + (size_t)(c << 2) * 512);
  float2 s = p[t];
  float2 s1 = p[t + 256], s2 = p[t + 512], s3 = p[t + 768];
  s.x += s1.x + s2.x + s3.x;
  s.y += s1.y + s2.y + s3.y;
  ((float2*)(centers + (size_t)c * 512))[t] = s;
  const int cnt = counts[c];
  if (cnt == 0) return;
  float ssq = s.x * s.x + s.y * s.y;
  ssq = waveRed(ssq);
  __shared__ float red[4];
  if ((t & 63) == 0) red[t >> 6] = ssq;
  __syncthreads();
  if (t == 0)
    atomicAdd(out, (red[0] + red[1] + red[2] + red[3]) / (float)cnt);
}

// vout[row] = badd[row] + sum_k W[row,K] vin[k]; one block per row (fp32 exact)
__global__ __launch_bounds__(256) void matvec_k(const float* __restrict__ W,
    const float* __restrict__ vin, const float* __restrict__ badd,
    float* __restrict__ vout, int K) {
  int row = blockIdx.x;
  float s = 0.f;
  for (int k = threadIdx.x; k < K; k += 256) s += W[(size_t)row * K + k] * vin[k];
  s = waveRed(s);
  __shared__ float red[4];
  if ((threadIdx.x & 63) == 0) red[threadIdx.x >> 6] = s;
  __syncthreads();
  if (threadIdx.x == 0) vout[row] = red[0] + red[1] + red[2] + red[3] + badd[row];
}

// ---------------------------------------------------------------------------
// pk class-sum kernel: sum over batch of the label-column logit, per level.
// ---------------------------------------------------------------------------
__global__ void pk_k(const float* __restrict__ centers,
                     const unsigned char* __restrict__ Bcat8,
                     const float* __restrict__ biascat,
                     const int* __restrict__ counts, float* __restrict__ scal) {
  const int b = blockIdx.x;           // [0, 3*512)
  const int lvl = b >> 9;
  const int c = b & 511;
  const int lane = threadIdx.x;       // 64 threads
  const int cbase = (lvl == 0) ? 0 : (lvl == 1) ? 2048 : 3072;
  const float4* S = (const float4*)(centers + (size_t)c * 512);
  const uint2 wb = ((const uint2*)(Bcat8 + (size_t)(cbase + c) * 512))[lane];
  const float4 s0 = S[lane * 2];
  const float4 s1 = S[lane * 2 + 1];
  float s = s0.x * fp8b0(wb.x) + s0.y * fp8b1(wb.x) +
            s0.z * fp8b2(wb.x) + s0.w * fp8b3(wb.x) +
            s1.x * fp8b0(wb.y) + s1.y * fp8b1(wb.y) +
            s1.z * fp8b2(wb.y) + s1.w * fp8b3(wb.y);
  s = waveRed(s);
  if (lane == 0)
    atomicAdd(&scal[5 + lvl], s + (float)counts[c] * biascat[cbase + c]);
}

// ---------------------------------------------------------------------------
// MX-fp8 GEMM for weight collapse: C[M,N] = A[M,K] @ B[N,K]^T, fp8 out
// ---------------------------------------------------------------------------
__global__ __launch_bounds__(256) void gemm8_w(
    const unsigned char* __restrict__ A8, const unsigned char* __restrict__ B8,
    int M, int N, int K, unsigned char* __restrict__ C8,
    unsigned char* __restrict__ Ct8) {
  __shared__ __align__(16) unsigned char As[128 * 128];
  __shared__ __align__(16) unsigned char Bs[128 * 128];
  const int tid = threadIdx.x;
  const int lane = tid & 63;
  const int wave = tid >> 6;
  const int lane16 = lane & 15;
  const int quad = lane >> 4;
  const int wm = (wave >> 1) * 64;
  const int wn = (wave & 1) * 64;
  const int m0 = blockIdx.y * 128;
  const int n0 = blockIdx.x * 128;

  f32x4 acc[4][4] = {};

  int srow[4], goff[4];
#pragma unroll
  for (int q = 0; q < 4; ++q) {
    const int s = tid + q * 256;
    const int row = s >> 3;
    const int c16 = s & 7;
    srow[q] = row;
    goff[q] = (((c16 >> 1) ^ (row & 3)) << 5) + ((c16 & 1) << 4);
  }

  for (int kt = 0; kt < K; kt += 128) {
#pragma unroll
    for (int q = 0; q < 4; ++q) {
      const int s = tid + q * 256;
      gload16(A8 + (size_t)(m0 + srow[q]) * K + kt + goff[q], &As[s * 16]);
      gload16(B8 + (size_t)(n0 + srow[q]) * K + kt + goff[q], &Bs[s * 16]);
    }
    __syncthreads();
    i32x8v a8[4], b8[4];
#pragma unroll
    for (int i = 0; i < 4; ++i) {
      const int row = i * 16 + lane16;
      const int sc = quad ^ (row & 3);
      const unsigned char* pa = &As[row * 128 + sc * 32];
      const i32x4v lo = *(const i32x4v*)pa;
      const i32x4v hi = *(const i32x4v*)(pa + 16);
      a8[i] = (i32x8v){lo[0], lo[1], lo[2], lo[3], hi[0], hi[1], hi[2], hi[3]};
    }
#pragma unroll
    for (int j = 0; j < 4; ++j) {
      const int row = j * 16 + lane16;
      const int sc = quad ^ (row & 3);
      const unsigned char* pb = &Bs[row * 128 + sc * 32];
      const i32x4v lo = *(const i32x4v*)pb;
      const i32x4v hi = *(const i32x4v*)(pb + 16);
      b8[j] = (i32x8v){lo[0], lo[1], lo[2], lo[3], hi[0], hi[1], hi[2], hi[3]};
    }
#pragma unroll
    for (int i = 0; i < 4; ++i)
#pragma unroll
      for (int j = 0; j < 4; ++j)
        acc[i][j] = __builtin_amdgcn_mfma_scale_f32_16x16x128_f8f6f4(
            a8[i], b8[j], acc[i][j], 0, 0, 0, 0x7f7f7f7f, 0, 0x7f7f7f7f);
    __syncthreads();
  }
#pragma unroll
  for (int i = 0; i < 4; ++i)
#pragma unroll
    for (int r = 0; r < 4; ++r) {
      const int rowg = m0 + wm + i * 16 + quad * 4 + r;
#pragma unroll
      for (int j = 0; j < 4; ++j) {
        const int colg = n0 + wn + j * 16 + lane16;
        const unsigned char v8 = f2fp8(acc[i][j][r]);
        C8[(size_t)rowg * N + colg] = v8;
        if (Ct8) Ct8[(size_t)colg * M + rowg] = v8;
      }
    }
}

// ---------------------------------------------------------------------------
// reorder: Bcat8 row-major (3584 x 512) -> fragment-major Bp, LDS-friendly.
// (lo/hi 16B split per lane; see round-3 comment)
// ---------------------------------------------------------------------------
__global__ void reorder_k(const unsigned char* __restrict__ in,
                          unsigned char* __restrict__ out) {
  const int id = blockIdx.x * 256 + threadIdx.x;   // 57344 chunks
  const int col = id >> 4;
  const int k32 = id & 15;                         // k/32
  const int kt = k32 >> 2, quad = k32 & 3;
  const int l = quad * 16 + (col & 15);
  const size_t src = (size_t)col * 512 + k32 * 32;
  const size_t fragbase = (size_t)(col >> 6) * 32768 + (size_t)kt * 8192 +
                          (size_t)((col >> 4) & 3) * 2048;
  const uint4 a = *(const uint4*)(in + src);        // k-bytes 0-15
  const uint4 b = *(const uint4*)(in + src + 16);   // k-bytes 16-31
  *(uint4*)(out + fragbase + l * 16) = a;
  *(uint4*)(out + fragbase + 1024 + l * 16) = b;
}

// ---------------------------------------------------------------------------
// Streaming fused logits+CE GEMM — software-pipelined, ALL-NAMED-REGS variant.
// Identical schedule to round 4 (vmcnt(4) 4-slot ring, raw barrier,
// lgkmcnt(8)+sched_barrier, setprio around MFMA cluster). The ONE change:
// every MFMA operand (A fragments a00..a13, B ping-pong bx0..3/by0..3,
// accumulators acc00..acc13) is a named SSA value built by value-returning
// helpers — rounds 2-4 used i32x8v arrays which the compiler demoted to
// scratch (VGPR_Count 84-92 << the ~190 needed), turning every k-step into
// a ~600cyc scratch reload inside the sched-pinned region. Diagnostic tell:
// VGPR_Count must now be ~150-180.
// ---------------------------------------------------------------------------
__global__ __launch_bounds__(256, 2) void gemm_ce8(
    const float* __restrict__ x, const unsigned char* __restrict__ Bp,
    const float* __restrict__ bias, float* __restrict__ scal) {
  __shared__ __align__(16) unsigned char Bl[4][8192];
  __shared__ float biasl[3584];
  const int tid = threadIdx.x;
  const int lane = tid & 63;
  const int wave = tid >> 6;
  const int lane16 = lane & 15;
  const int quad = lane >> 4;
  const int m0 = blockIdx.x * 128 + wave * 32;

  // ---- bias -> LDS (once) ----
  for (int i = tid; i < 3584; i += 256) biasl[i] = bias[i];

  // ---- A: 32 rows x 512 fp8 in NAMED VGPRs, fused fp32->fp8 ----
  const float* xr0 = x + (size_t)(m0 + lane16) * 512 + quad * 32;
  const float* xr1 = x + (size_t)(m0 + 16 + lane16) * 512 + quad * 32;
  i32x8v a00 = cvt32(xr0);
  i32x8v a01 = cvt32(xr0 + 128);
  i32x8v a02 = cvt32(xr0 + 256);
  i32x8v a03 = cvt32(xr0 + 384);
  i32x8v a10 = cvt32(xr1);
  i32x8v a11 = cvt32(xr1 + 128);
  i32x8v a12 = cvt32(xr1 + 256);
  i32x8v a13 = cvt32(xr1 + 384);
  __syncthreads();  // biasl visible; vmcnt/lgkmcnt drained (full sync)

  // ---- pipeline prologue: stage chunks 0,1,2 ----
  const int soff = wave * 2048 + lane * 16;
  const unsigned char* bsrc = Bp + soff;
#pragma unroll
  for (int c = 0; c < 3; ++c) {
    gload16(bsrc, &Bl[c][soff]);
    gload16(bsrc + 1024, &Bl[c][soff + 1024]);
    bsrc += 8192;
  }
  int sc = 3;  // chunk index bsrc points at (224 chunks total)
  asm volatile("s_waitcnt vmcnt(4)" ::: "memory");  // chunk 0 resident
  __builtin_amdgcn_s_barrier();

  // preload chunk 0 -> bx (waited by first KSTEP's lgkmcnt(8))
  const int l16 = lane * 16;
  i32x8v bx0, bx1, bx2, bx3, by0, by1, by2, by3;
  {
    const unsigned char* bb = &Bl[0][0];
    bx0 = ldfrag(bb, l16);
    bx1 = ldfrag(bb, 2048 + l16);
    bx2 = ldfrag(bb, 4096 + l16);
    bx3 = ldfrag(bb, 6144 + l16);
  }

  float es[8];
#pragma unroll
  for (int k = 0; k < 8; ++k) es[k] = 0.f;

#define MFMA8(A0, A1, B0, B1, B2, B3)                                         \
  acc00 = __builtin_amdgcn_mfma_scale_f32_16x16x128_f8f6f4(                   \
      A0, B0, acc00, 0, 0, 0, 0x7f7f7f7f, 0, 0x7f7f7f7f);                     \
  acc01 = __builtin_amdgcn_mfma_scale_f32_16x16x128_f8f6f4(                   \
      A0, B1, acc01, 0, 0, 0, 0x7f7f7f7f, 0, 0x7f7f7f7f);                     \
  acc02 = __builtin_amdgcn_mfma_scale_f32_16x16x128_f8f6f4(                   \
      A0, B2, acc02, 0, 0, 0, 0x7f7f7f7f, 0, 0x7f7f7f7f);                     \
  acc03 = __builtin_amdgcn_mfma_scale_f32_16x16x128_f8f6f4(                   \
      A0, B3, acc03, 0, 0, 0, 0x7f7f7f7f, 0, 0x7f7f7f7f);                     \
  acc10 = __builtin_amdgcn_mfma_scale_f32_16x16x128_f8f6f4(                   \
      A1, B0, acc10, 0, 0, 0, 0x7f7f7f7f, 0, 0x7f7f7f7f);                     \
  acc11 = __builtin_amdgcn_mfma_scale_f32_16x16x128_f8f6f4(                   \
      A1, B1, acc11, 0, 0, 0, 0x7f7f7f7f, 0, 0x7f7f7f7f);                     \
  acc12 = __builtin_amdgcn_mfma_scale_f32_16x16x128_f8f6f4(                   \
      A1, B2, acc12, 0, 0, 0, 0x7f7f7f7f, 0, 0x7f7f7f7f);                     \
  acc13 = __builtin_amdgcn_mfma_scale_f32_16x16x128_f8f6f4(                   \
      A1, B3, acc13, 0, 0, 0, 0x7f7f7f7f, 0, 0x7f7f7f7f);

#define KSTEP(KS, BC0, BC1, BC2, BC3, BN0, BN1, BN2, BN3, A0, A1)             \
  {                                                                           \
    gload16(bsrc, &Bl[(KS + 3) & 3][soff]);                                   \
    gload16(bsrc + 1024, &Bl[(KS + 3) & 3][soff + 1024]);                     \
    bsrc += 8192;                                                             \
    if (++sc == 224) { sc = 0; bsrc = Bp + soff; }                            \
    asm volatile("s_waitcnt vmcnt(4)" ::: "memory");                          \
    __builtin_amdgcn_s_barrier();                                             \
    {                                                                         \
      const unsigned char* bb = &Bl[(KS + 1) & 3][0];                         \
      BN0 = ldfrag(bb, l16);                                                  \
      BN1 = ldfrag(bb, 2048 + l16);                                           \
      BN2 = ldfrag(bb, 4096 + l16);                                           \
      BN3 = ldfrag(bb, 6144 + l16);                                           \
    }                                                                         \
    asm volatile("s_waitcnt lgkmcnt(8)" ::: "memory");                        \
    __builtin_amdgcn_sched_barrier(0);                                        \
    __builtin_amdgcn_s_setprio(1);                                            \
    MFMA8(A0, A1, BC0, BC1, BC2, BC3)                                         \
    __builtin_amdgcn_s_setprio(0);                                            \
  }

  int tile = 0;
#pragma unroll 1
  for (int lvl = 0; lvl < 3; ++lvl) {
    const int nt = (lvl == 0) ? 32 : (lvl == 1) ? 16 : 8;
#pragma unroll 1
    for (int t = 0; t < nt; ++t, ++tile) {
      f32x4 acc00 = {}, acc01 = {}, acc02 = {}, acc03 = {};
      f32x4 acc10 = {}, acc11 = {}, acc12 = {}, acc13 = {};
      KSTEP(0, bx0, bx1, bx2, bx3, by0, by1, by2, by3, a00, a10)
      KSTEP(1, by0, by1, by2, by3, bx0, bx1, bx2, bx3, a01, a11)
      KSTEP(2, bx0, bx1, bx2, bx3, by0, by1, by2, by3, a02, a12)
      KSTEP(3, by0, by1, by2, by3, bx0, bx1, bx2, bx3, a03, a13)
      // ---- register CE epilogue (bias from LDS; pk handled by pk_k) ----
      const float bj0 = biasl[tile * 64 + lane16];
      const float bj1 = biasl[tile * 64 + 16 + lane16];
      const float bj2 = biasl[tile * 64 + 32 + lane16];
      const float bj3 = biasl[tile * 64 + 48 + lane16];
#pragma unroll
      for (int r = 0; r < 4; ++r) {
        es[r] += __expf(acc00[r] + bj0) + __expf(acc01[r] + bj1) +
                 __expf(acc02[r] + bj2) + __expf(acc03[r] + bj3);
        es[4 + r] += __expf(acc10[r] + bj0) + __expf(acc11[r] + bj1) +
                     __expf(acc12[r] + bj2) + __expf(acc13[r] + bj3);
      }
    }
    // ---- level close: reduce es over lane16, log, accumulate ----
    float ls = 0.f;
#pragma unroll
    for (int k = 0; k < 8; ++k) {
      float tot = es[k];
      tot += __shfl_xor(tot, 1, 64);
      tot += __shfl_xor(tot, 2, 64);
      tot += __shfl_xor(tot, 4, 64);
      tot += __shfl_xor(tot, 8, 64);
      if (lane16 == 0) ls += __logf(tot);
      es[k] = 0.f;
    }
    ls = waveRed(ls);
    if (lane == 0) atomicAdd(&scal[2 + lvl], ls);
  }
#undef KSTEP
#undef MFMA8
}

// scal: [0]=sumsq_x [1]=sum ||sums_c||^2/n_c [2..4]=logsumexp sums [5..7]=pk sums
__global__ void fin_k(const float* __restrict__ scal, const float* __restrict__ lam,
                      float* __restrict__ out, float invB) {
  if (threadIdx.x == 0 && blockIdx.x == 0)
    out[0] = lam[0] * (scal[0] - scal[1]) +
             (lam[1] * (scal[2] - scal[5]) + lam[2] * (scal[3] - scal[6]) +
              lam[3] * (scal[4] - scal[7])) * invB;
}

// ---------------------------------------------------------------------------
// Launch
// ---------------------------------------------------------------------------
extern "C" void kernel_launch(void* const* d_in, const int* in_sizes, int n_in,
                              void* d_out, int out_size, void* d_ws, size_t ws_size,
                              hipStream_t stream) {
  const float* x   = (const float*)d_in[0];
  const float* W0  = (const float*)d_in[1];
  const float* b0  = (const float*)d_in[2];
  const float* W1  = (const float*)d_in[3];
  const float* b1  = (const float*)d_in[4];
  const float* W2  = (const float*)d_in[5];
  const float* b2  = (const float*)d_in[6];
  const float* lam = (const float*)d_in[7];
  const int*   lab = (const int*)d_in[8];

  const int Bsz = in_sizes[8];         // 65536
  const int D   = in_sizes[0] / Bsz;   // 512
  const int N0  = in_sizes[2];         // 2048
  const int N1  = in_sizes[4];         // 1024
  const int N2  = in_sizes[6];         // 512
  const int Ncat = N0 + N1 + N2;       // 3584
  const int NCLS = 512;

  char* w = (char*)d_ws;
  size_t off = 0;
  auto alloc = [&](size_t bytes) -> void* {
    void* p = w + off;
    off += (bytes + 255) & ~(size_t)255;
    return p;
  };

  unsigned char* Bcat8 = (unsigned char*)alloc((size_t)Ncat * D);         // row-major
  unsigned char* Bp    = (unsigned char*)alloc((size_t)Ncat * D + 16384); // frag-major (+slack)
  unsigned char* W1_8  = (unsigned char*)alloc((size_t)N1 * N0);
  unsigned char* W2_8  = (unsigned char*)alloc((size_t)N2 * N1);
  unsigned char* W0t8  = (unsigned char*)alloc((size_t)D * N0);
  unsigned char* M1t8  = (unsigned char*)alloc((size_t)D * N1);
  float* biascat  = (float*)alloc((size_t)Ncat * 4);
  int* offsets = (int*)alloc(NCLS * 4);
  int* cursor  = (int*)alloc(NCLS * 4);
  int* buckets = (int*)alloc((size_t)Bsz * 4);
  float* centers4 = (float*)alloc((size_t)NCLS * 512 * 4 * 4);  // partials (no zero)
  float* centers  = (float*)alloc((size_t)NCLS * 512 * 4);      // summed (no zero)
  // zero region: counts(512i) | scal(8f)
  const int zwords = NCLS + 8;
  char* zr = (char*)alloc((size_t)zwords * 4);
  int*   counts  = (int*)zr;
  float* scal    = (float*)(zr + NCLS * 4);
  (void)ws_size; (void)n_in; (void)out_size;

  // fused prep: weight fp8 conversions + W0^T + zero + b0 copy
  const int zb = (zwords + 255) / 256;
  prep_w<<<dim3(1792 + zb + 8), dim3(256), 0, stream>>>(
      (const float4*)W1, (const float4*)W2, (const float4*)W0, W0, b0,
      (uint32_t*)W1_8, (uint32_t*)W2_8, (uint32_t*)Bcat8, W0t8,
      (float*)zr, zwords, biascat);

  // center-loss bucketing + class partial sums (plain stores) + batch sumsq
  count_k<<<dim3(32), dim3(256), 0, stream>>>(lab, counts, Bsz);
  prefix_k<<<dim3(1), dim3(64), 0, stream>>>(counts, offsets, cursor, NCLS);
  scatter_k<<<dim3(256), dim3(256), 0, stream>>>(lab, cursor, buckets, Bsz);
  csum_k<<<dim3(4 * NCLS), dim3(256), 0, stream>>>(x, buckets, offsets, counts,
                                                   centers4, scal);
  cnorm_k<<<dim3(NCLS), dim3(256), 0, stream>>>(centers4, centers, counts,
                                                &scal[1]);

  // collapsed biases: biascat = [b0 | b1 + W1 b0 | b2 + W2 c1] (fp32 exact)
  matvec_k<<<dim3(N1), dim3(256), 0, stream>>>(W1, b0, b1, biascat + N0, N0);
  matvec_k<<<dim3(N2), dim3(256), 0, stream>>>(W2, biascat + N0, b2, biascat + N0 + N1, N1);

  // collapsed weights (fp8): M1 = W1@W0 -> Bcat8 seg1 + M1t8; M2 = W2@M1 -> seg2
  gemm8_w<<<dim3(D / 128, N1 / 128), dim3(256), 0, stream>>>(
      W1_8, W0t8, N1, D, N0, Bcat8 + (size_t)N0 * D, M1t8);
  gemm8_w<<<dim3(D / 128, N2 / 128), dim3(256), 0, stream>>>(
      W2_8, M1t8, N2, D, N1, Bcat8 + (size_t)(N0 + N1) * D, nullptr);

  // row-major -> fragment-major (LDS-friendly lo/hi split)
  reorder_k<<<dim3(Ncat * D / 32 / 256), dim3(256), 0, stream>>>(Bcat8, Bp);

  // pk via class-sum identity (needs Bcat8 complete + centers + biascat + counts)
  pk_k<<<dim3(3 * NCLS), dim3(64), 0, stream>>>(centers, Bcat8, biascat,
                                                counts, scal);

  // software-pipelined streaming fused logits+CE (all three levels)
  gemm_ce8<<<dim3(Bsz / 128), dim3(256), 0, stream>>>(x, Bp, biascat, scal);

  fin_k<<<dim3(1), dim3(64), 0, stream>>>(scal, lam, (float*)d_out, 1.f / (float)Bsz);
}